// Round 10
// baseline (125.352 us; speedup 1.0000x reference)
//
#include <hip/hip_runtime.h>
#include <hip/hip_bf16.h>

#define NROWS 4096
#define TWO_N 8192
#define DDIM 64
#define INV_T 20.0f
// exp(dot*INV_T) = 2^(dot*INV_T*log2e); fold sqrt of that scale into each operand
#define SCALE2 5.3716292f   // sqrt(20 * 1.4426950408889634)
#define CHUNKS 32
#define CPC 256            // columns per chunk
#define JT 4               // 64-col steps per chunk

typedef short bf16x8 __attribute__((ext_vector_type(8)));
typedef float f32x4 __attribute__((ext_vector_type(4)));

__device__ __forceinline__ unsigned short f32_to_bf16_rne(float f) {
    unsigned int u = __float_as_uint(f);
    return (unsigned short)((u + 0x7fffu + ((u >> 16) & 1u)) >> 16);
}

__device__ __forceinline__ float fast_exp2(float x) {
    float r;
    asm("v_exp_f32 %0, %1" : "=v"(r) : "v"(x));
    return r;
}

// featsT fragment-major layout: element (row=16g+lr, col=kb*32+lk*8+e) at
//   featsT[g*1024 + kb*512 + (lk*16+lr)*8 + e]
// -> an MFMA fragment load is featsT + g*1024 + kb*512 + lane*8 (1KB coalesced).

// ---- kernel 1: convert f32 -> scaled bf16 fragment-major + posdot + zero out ----
__global__ void prep_kernel(const float* __restrict__ f1,
                            const float* __restrict__ f2,
                            unsigned short* __restrict__ featsT,
                            float* __restrict__ posdot,
                            float* __restrict__ out) {
    if (blockIdx.x == 0 && threadIdx.x == 0) out[0] = 0.f;
    int t = blockIdx.x * blockDim.x + threadIdx.x;
    int r = t >> 4;
    int q = t & 15;
    int j = r * DDIM + q * 4;
    float4 a = *reinterpret_cast<const float4*>(&f1[j]);
    float4 b = *reinterpret_cast<const float4*>(&f2[j]);
    // posdot from unscaled values (f32-exact path)
    float d = a.x * b.x + a.y * b.y + a.z * b.z + a.w * b.w;
    d += __shfl_xor(d, 1);
    d += __shfl_xor(d, 2);
    d += __shfl_xor(d, 4);
    d += __shfl_xor(d, 8);
    if (q == 0) posdot[r] = d * INV_T;
    // scaled bf16 store, fragment-major
    ushort4 ua = make_ushort4(f32_to_bf16_rne(a.x * SCALE2), f32_to_bf16_rne(a.y * SCALE2),
                              f32_to_bf16_rne(a.z * SCALE2), f32_to_bf16_rne(a.w * SCALE2));
    ushort4 ub = make_ushort4(f32_to_bf16_rne(b.x * SCALE2), f32_to_bf16_rne(b.y * SCALE2),
                              f32_to_bf16_rne(b.z * SCALE2), f32_to_bf16_rne(b.w * SCALE2));
    int g1 = r >> 4;
    int lr = r & 15;
    int kb = q >> 3;
    int lk = (q & 7) >> 1;
    int e  = (q & 1) * 4;
    int off = g1 * 1024 + kb * 512 + (lk * 16 + lr) * 8 + e;
    *reinterpret_cast<ushort4*>(&featsT[off]) = ua;                 // f1: groups 0..255
    *reinterpret_cast<ushort4*>(&featsT[off + 256 * 1024]) = ub;    // f2: groups 256..511
}

// ---- kernel 2: NgPart[row][chunk] = sum_{j in chunk, lab_j != lab_i} exp(dot_ij/T) ----
// Block: 128 rows x 256-col chunk. 4 waves, each owning a disjoint 32-row slice.
// Atomic-free: plain stores to NgPart. ~96 VGPR, no spill, 2048 blocks for slack.
__global__ __launch_bounds__(256, 4) void ng_kernel(const unsigned short* __restrict__ featsT,
                                                    const int* __restrict__ label,
                                                    float* __restrict__ NgPart) {
    __shared__ int clabS[CPC];
    __shared__ int rlabS[128];
    const int tid = threadIdx.x;
    const int rowBase = blockIdx.y * 128;
    const int chunk = blockIdx.x;
    const int colBase = chunk * CPC;
    if (tid < CPC) clabS[tid] = label[(colBase + tid) & (NROWS - 1)];
    if (tid >= 128 && tid < 256) rlabS[tid - 128] = label[(rowBase + tid - 128) & (NROWS - 1)];
    __syncthreads();

    const int wid = tid >> 6;
    const int lane = tid & 63;
    const int lr = lane & 15;
    const int lk = lane >> 4;
    const int wr = wid * 32;                 // this wave's 32-row slice
    const int gr0 = (rowBase + wr) >> 4;
    const int gc0 = colBase >> 4;

    // A fragments: resident for the whole block, coalesced
    bf16x8 afr[2][2];
    #pragma unroll
    for (int kb = 0; kb < 2; ++kb)
        #pragma unroll
        for (int m = 0; m < 2; ++m)
            afr[kb][m] = *reinterpret_cast<const bf16x8*>(
                &featsT[(gr0 + m) * 1024 + kb * 512 + lane * 8]);

    int rl[2][4];
    #pragma unroll
    for (int m = 0; m < 2; ++m)
        #pragma unroll
        for (int r = 0; r < 4; ++r)
            rl[m][r] = rlabS[wr + m * 16 + lk * 4 + r];

    float rsum[2][4];
    #pragma unroll
    for (int m = 0; m < 2; ++m)
        #pragma unroll
        for (int r = 0; r < 4; ++r) rsum[m][r] = 0.f;

    #pragma unroll
    for (int jt = 0; jt < JT; ++jt) {
        f32x4 acc[2][4];
        f32x4 zero = {0.f, 0.f, 0.f, 0.f};
        #pragma unroll
        for (int m = 0; m < 2; ++m)
            #pragma unroll
            for (int n = 0; n < 4; ++n) acc[m][n] = zero;

        #pragma unroll
        for (int kb = 0; kb < 2; ++kb) {
            bf16x8 bfr[4];
            #pragma unroll
            for (int n = 0; n < 4; ++n)
                bfr[n] = *reinterpret_cast<const bf16x8*>(
                    &featsT[(gc0 + jt * 4 + n) * 1024 + kb * 512 + lane * 8]);
            #pragma unroll
            for (int m = 0; m < 2; ++m)
                #pragma unroll
                for (int n = 0; n < 4; ++n)
                    acc[m][n] = __builtin_amdgcn_mfma_f32_16x16x32_bf16(afr[kb][m], bfr[n], acc[m][n], 0, 0, 0);
        }

        int cl[4];
        #pragma unroll
        for (int n = 0; n < 4; ++n) cl[n] = clabS[jt * 64 + n * 16 + lr];

        #pragma unroll
        for (int m = 0; m < 2; ++m)
            #pragma unroll
            for (int r = 0; r < 4; ++r) {
                int lab = rl[m][r];
                float s = 0.f;
                #pragma unroll
                for (int n = 0; n < 4; ++n) {
                    float e = fast_exp2(acc[m][n][r]);   // = exp(dot/T)
                    s += (cl[n] != lab) ? e : 0.f;
                }
                rsum[m][r] += s;
            }
    }

    // reduce across the 16 lr lanes; plain store (no atomics)
    #pragma unroll
    for (int m = 0; m < 2; ++m)
        #pragma unroll
        for (int r = 0; r < 4; ++r) {
            float v = rsum[m][r];
            v += __shfl_xor(v, 1);
            v += __shfl_xor(v, 2);
            v += __shfl_xor(v, 4);
            v += __shfl_xor(v, 8);
            if (lr == 0)
                NgPart[(size_t)(rowBase + wr + m * 16 + lk * 4 + r) * CHUNKS + chunk] = v;
        }
}

// ---- kernel 3: final loss (16 blocks x 256 threads, coalesced partial reduce) ----
__global__ void final_kernel(const float* __restrict__ NgPart,
                             const float* __restrict__ posdot,
                             const int* __restrict__ label,
                             float* __restrict__ out) {
    __shared__ int cnt[16];
    __shared__ float red[4];
    int tid = threadIdx.x;
    if (tid < 16) cnt[tid] = 0;
    __syncthreads();
    for (int i = tid; i < NROWS; i += 256) atomicAdd(&cnt[label[i]], 1);
    __syncthreads();
    float s = 0.f;
    #pragma unroll
    for (int k = 0; k < 2; ++k) {
        int i = blockIdx.x * 512 + k * 256 + tid;
        float ng = 0.f;
        #pragma unroll
        for (int c = 0; c < CHUNKS / 4; ++c) {
            float4 p = *reinterpret_cast<const float4*>(&NgPart[(size_t)i * CHUNKS + c * 4]);
            ng += p.x + p.y + p.z + p.w;
        }
        int base = i & (NROWS - 1);
        float pd = posdot[base];
        float gs = 2.0f * (float)cnt[label[base]];
        s += (__logf(ng + __expf(pd)) - pd) / gs;
    }
    #pragma unroll
    for (int m = 32; m; m >>= 1) s += __shfl_xor(s, m);
    if ((tid & 63) == 0) red[tid >> 6] = s;
    __syncthreads();
    if (tid == 0) atomicAdd(out, red[0] + red[1] + red[2] + red[3]);
}

extern "C" void kernel_launch(void* const* d_in, const int* in_sizes, int n_in,
                              void* d_out, int out_size, void* d_ws, size_t ws_size,
                              hipStream_t stream) {
    const float* f1 = (const float*)d_in[0];
    const float* f2 = (const float*)d_in[1];
    const int* label = (const int*)d_in[2];
    float* out = (float*)d_out;

    char* ws = (char*)d_ws;
    unsigned short* featsT = (unsigned short*)ws;                           // 1 MB
    float* NgPart = (float*)(ws + (size_t)TWO_N * DDIM * 2);                // 1 MB
    float* posdot = (float*)(ws + (size_t)TWO_N * DDIM * 2 + (size_t)TWO_N * CHUNKS * 4);  // 16 KB

    prep_kernel<<<dim3(NROWS * DDIM / 4 / 256), dim3(256), 0, stream>>>(f1, f2, featsT, posdot, out);
    ng_kernel<<<dim3(CHUNKS, TWO_N / 128), dim3(256), 0, stream>>>(featsT, label, NgPart);
    final_kernel<<<dim3(TWO_N / 512), dim3(256), 0, stream>>>(NgPart, posdot, label, out);
}

// Round 11
// 84.621 us; speedup vs baseline: 1.4813x; 1.4813x over previous
//
#include <hip/hip_runtime.h>
#include <hip/hip_bf16.h>

#define NROWS 4096
#define TWO_N 8192
#define DDIM 64
#define INV_T 20.0f
// exp(dot*INV_T) = 2^(dot*INV_T*log2e); fold sqrt of that scale into each operand
#define SCALE2 5.3716292f   // sqrt(20 * 1.4426950408889634)
#define CHUNKS 32
#define CPC 256            // columns per chunk
#define JT 4               // 64-col steps per chunk

typedef short bf16x8 __attribute__((ext_vector_type(8)));
typedef float f32x4 __attribute__((ext_vector_type(4)));

__device__ __forceinline__ unsigned short f32_to_bf16_rne(float f) {
    unsigned int u = __float_as_uint(f);
    return (unsigned short)((u + 0x7fffu + ((u >> 16) & 1u)) >> 16);
}

__device__ __forceinline__ float fast_exp2(float x) {
    float r;
    asm("v_exp_f32 %0, %1" : "=v"(r) : "v"(x));
    return r;
}

// featsT fragment-major layout: element (row=16g+lr, col=kb*32+lk*8+e) at
//   featsT[g*1024 + kb*512 + (lk*16+lr)*8 + e]
// -> an MFMA fragment load is featsT + g*1024 + kb*512 + lane*8 (1KB coalesced).

// ---- kernel 1: convert f32 -> scaled bf16 fragment-major + posdot + zero out ----
__global__ void prep_kernel(const float* __restrict__ f1,
                            const float* __restrict__ f2,
                            unsigned short* __restrict__ featsT,
                            float* __restrict__ posdot,
                            float* __restrict__ out) {
    if (blockIdx.x == 0 && threadIdx.x == 0) out[0] = 0.f;
    int t = blockIdx.x * blockDim.x + threadIdx.x;
    int r = t >> 4;
    int q = t & 15;
    int j = r * DDIM + q * 4;
    float4 a = *reinterpret_cast<const float4*>(&f1[j]);
    float4 b = *reinterpret_cast<const float4*>(&f2[j]);
    // posdot from unscaled values (f32-exact path)
    float d = a.x * b.x + a.y * b.y + a.z * b.z + a.w * b.w;
    d += __shfl_xor(d, 1);
    d += __shfl_xor(d, 2);
    d += __shfl_xor(d, 4);
    d += __shfl_xor(d, 8);
    if (q == 0) posdot[r] = d * INV_T;
    // scaled bf16 store, fragment-major
    ushort4 ua = make_ushort4(f32_to_bf16_rne(a.x * SCALE2), f32_to_bf16_rne(a.y * SCALE2),
                              f32_to_bf16_rne(a.z * SCALE2), f32_to_bf16_rne(a.w * SCALE2));
    ushort4 ub = make_ushort4(f32_to_bf16_rne(b.x * SCALE2), f32_to_bf16_rne(b.y * SCALE2),
                              f32_to_bf16_rne(b.z * SCALE2), f32_to_bf16_rne(b.w * SCALE2));
    int g1 = r >> 4;
    int lr = r & 15;
    int kb = q >> 3;
    int lk = (q & 7) >> 1;
    int e  = (q & 1) * 4;
    int off = g1 * 1024 + kb * 512 + (lk * 16 + lr) * 8 + e;
    *reinterpret_cast<ushort4*>(&featsT[off]) = ua;                 // f1: groups 0..255
    *reinterpret_cast<ushort4*>(&featsT[off + 256 * 1024]) = ub;    // f2: groups 256..511
}

// ---- kernel 2: NgPart[row][chunk] = sum_{j in chunk, lab_j != lab_i} exp(dot_ij/T) ----
// Block: 128 rows x 256-col chunk. 4 waves, each owning a disjoint 32-row slice.
// Atomic-free plain stores. jt loop kept ROLLED (#pragma unroll 1) and no
// min-waves launch bound: both are required to stay ~100 VGPR with zero spill
// (round-10: full unroll + waves-per-eu=4 -> 64 VGPR + 215 MB scratch traffic).
__global__ __launch_bounds__(256) void ng_kernel(const unsigned short* __restrict__ featsT,
                                                 const int* __restrict__ label,
                                                 float* __restrict__ NgPart) {
    __shared__ int clabS[CPC];
    __shared__ int rlabS[128];
    const int tid = threadIdx.x;
    const int rowBase = blockIdx.y * 128;
    const int chunk = blockIdx.x;
    const int colBase = chunk * CPC;
    if (tid < CPC) clabS[tid] = label[(colBase + tid) & (NROWS - 1)];
    if (tid >= 128 && tid < 256) rlabS[tid - 128] = label[(rowBase + tid - 128) & (NROWS - 1)];
    __syncthreads();

    const int wid = tid >> 6;
    const int lane = tid & 63;
    const int lr = lane & 15;
    const int lk = lane >> 4;
    const int wr = wid * 32;                 // this wave's 32-row slice
    const int gr0 = (rowBase + wr) >> 4;
    const int gc0 = colBase >> 4;

    // A fragments: resident for the whole block, coalesced
    bf16x8 afr[2][2];
    #pragma unroll
    for (int kb = 0; kb < 2; ++kb)
        #pragma unroll
        for (int m = 0; m < 2; ++m)
            afr[kb][m] = *reinterpret_cast<const bf16x8*>(
                &featsT[(gr0 + m) * 1024 + kb * 512 + lane * 8]);

    int rl[2][4];
    #pragma unroll
    for (int m = 0; m < 2; ++m)
        #pragma unroll
        for (int r = 0; r < 4; ++r)
            rl[m][r] = rlabS[wr + m * 16 + lk * 4 + r];

    float rsum[2][4];
    #pragma unroll
    for (int m = 0; m < 2; ++m)
        #pragma unroll
        for (int r = 0; r < 4; ++r) rsum[m][r] = 0.f;

    #pragma unroll 1
    for (int jt = 0; jt < JT; ++jt) {
        f32x4 acc[2][4];
        f32x4 zero = {0.f, 0.f, 0.f, 0.f};
        #pragma unroll
        for (int m = 0; m < 2; ++m)
            #pragma unroll
            for (int n = 0; n < 4; ++n) acc[m][n] = zero;

        #pragma unroll
        for (int kb = 0; kb < 2; ++kb) {
            bf16x8 bfr[4];
            #pragma unroll
            for (int n = 0; n < 4; ++n)
                bfr[n] = *reinterpret_cast<const bf16x8*>(
                    &featsT[(gc0 + jt * 4 + n) * 1024 + kb * 512 + lane * 8]);
            #pragma unroll
            for (int m = 0; m < 2; ++m)
                #pragma unroll
                for (int n = 0; n < 4; ++n)
                    acc[m][n] = __builtin_amdgcn_mfma_f32_16x16x32_bf16(afr[kb][m], bfr[n], acc[m][n], 0, 0, 0);
        }

        int cl[4];
        #pragma unroll
        for (int n = 0; n < 4; ++n) cl[n] = clabS[jt * 64 + n * 16 + lr];

        #pragma unroll
        for (int m = 0; m < 2; ++m)
            #pragma unroll
            for (int r = 0; r < 4; ++r) {
                int lab = rl[m][r];
                float s = 0.f;
                #pragma unroll
                for (int n = 0; n < 4; ++n) {
                    float e = fast_exp2(acc[m][n][r]);   // = exp(dot/T)
                    s += (cl[n] != lab) ? e : 0.f;
                }
                rsum[m][r] += s;
            }
    }

    // reduce across the 16 lr lanes; plain store (no atomics)
    #pragma unroll
    for (int m = 0; m < 2; ++m)
        #pragma unroll
        for (int r = 0; r < 4; ++r) {
            float v = rsum[m][r];
            v += __shfl_xor(v, 1);
            v += __shfl_xor(v, 2);
            v += __shfl_xor(v, 4);
            v += __shfl_xor(v, 8);
            if (lr == 0)
                NgPart[(size_t)(rowBase + wr + m * 16 + lk * 4 + r) * CHUNKS + chunk] = v;
        }
}

// ---- kernel 3: final loss (16 blocks x 256 threads, coalesced partial reduce) ----
__global__ void final_kernel(const float* __restrict__ NgPart,
                             const float* __restrict__ posdot,
                             const int* __restrict__ label,
                             float* __restrict__ out) {
    __shared__ int cnt[16];
    __shared__ float red[4];
    int tid = threadIdx.x;
    if (tid < 16) cnt[tid] = 0;
    __syncthreads();
    for (int i = tid; i < NROWS; i += 256) atomicAdd(&cnt[label[i]], 1);
    __syncthreads();
    float s = 0.f;
    #pragma unroll
    for (int k = 0; k < 2; ++k) {
        int i = blockIdx.x * 512 + k * 256 + tid;
        float ng = 0.f;
        #pragma unroll
        for (int c = 0; c < CHUNKS / 4; ++c) {
            float4 p = *reinterpret_cast<const float4*>(&NgPart[(size_t)i * CHUNKS + c * 4]);
            ng += p.x + p.y + p.z + p.w;
        }
        int base = i & (NROWS - 1);
        float pd = posdot[base];
        float gs = 2.0f * (float)cnt[label[base]];
        s += (__logf(ng + __expf(pd)) - pd) / gs;
    }
    #pragma unroll
    for (int m = 32; m; m >>= 1) s += __shfl_xor(s, m);
    if ((tid & 63) == 0) red[tid >> 6] = s;
    __syncthreads();
    if (tid == 0) atomicAdd(out, red[0] + red[1] + red[2] + red[3]);
}

extern "C" void kernel_launch(void* const* d_in, const int* in_sizes, int n_in,
                              void* d_out, int out_size, void* d_ws, size_t ws_size,
                              hipStream_t stream) {
    const float* f1 = (const float*)d_in[0];
    const float* f2 = (const float*)d_in[1];
    const int* label = (const int*)d_in[2];
    float* out = (float*)d_out;

    char* ws = (char*)d_ws;
    unsigned short* featsT = (unsigned short*)ws;                           // 1 MB
    float* NgPart = (float*)(ws + (size_t)TWO_N * DDIM * 2);                // 1 MB
    float* posdot = (float*)(ws + (size_t)TWO_N * DDIM * 2 + (size_t)TWO_N * CHUNKS * 4);  // 16 KB

    prep_kernel<<<dim3(NROWS * DDIM / 4 / 256), dim3(256), 0, stream>>>(f1, f2, featsT, posdot, out);
    ng_kernel<<<dim3(CHUNKS, TWO_N / 128), dim3(256), 0, stream>>>(featsT, label, NgPart);
    final_kernel<<<dim3(TWO_N / 512), dim3(256), 0, stream>>>(NgPart, posdot, label, out);
}